// Round 11
// baseline (383.655 us; speedup 1.0000x reference)
//
#include <hip/hip_runtime.h>

// LSTM forward, T=2048, B=1024, I=15, H=10 (PyTorch gate order i,f,g,o).
// Producer/consumer wave specialization, one 128-thread block per batch row:
//   wave 0 (consumer, s_setprio(1)): serial recurrence, 16-level dependency chain
//   wave 1 (producer, prio 0):       x.Wih projection (f16 fdot2) -> LDS ring
// R10 measured: consumer step 402cy = R6 chain (310) + producer issue (~90):
// co-resident wave issue ADDS on an in-order SIMD. Fixes here:
//   (a) consumer runs at wave priority 1 -> producer issue pushed into true
//       chain-stall slots only (T5 mechanism: role-diverse waves on one SIMD).
//   (b) chain 17->16 levels: broadcast th=tanh(c) instead of h=o*th; fold each
//       unit's o into the dot weights (wov_q = o_q*wh_q, off-chain, computed
//       from readlanes of rc taken 7 levels ahead of use). Deletes the h-mul
//       from the serial cycle. h itself is computed off-chain for output only.
// Lane layout (consumer): lane = 4*j + p, j=hidden unit, p=gate; lanes 40..63
// dup j=9 (write-masked). Gate combine via DPP quad_perm. Weight prescale:
// sigmoid rows -log2e, tanh row +2log2e; g-gate act additionally scaled 2log2e
// so cell state is carried as cs = 2log2e*c and feeds exp2 directly.

#define T_N  2048
#define B_N  1024
#define I_N  15
#define H_N  10
#define DQ   32            // steps per LDS buffer
#define NBLK (T_N / DQ)    // 64 blocks
#define LPAD 64            // padded LDS row (unconditional producer writes)

typedef _Float16 half2_t __attribute__((ext_vector_type(2)));

template <int CTRL>
static __device__ __forceinline__ float dppf(float v) {
    return __builtin_bit_cast(float,
        __builtin_amdgcn_mov_dpp(__builtin_bit_cast(int, v), CTRL, 0xF, 0xF, true));
}
static __device__ __forceinline__ float rl(float v, int lane) {
    return __builtin_bit_cast(float, __builtin_amdgcn_readlane(__builtin_bit_cast(int, v), lane));
}
static __device__ __forceinline__ unsigned rlu(unsigned v, int lane) {
    return (unsigned)__builtin_amdgcn_readlane((int)v, lane);
}
static __device__ __forceinline__ half2_t h2(unsigned u) {
    return __builtin_bit_cast(half2_t, u);
}

// light barrier: LDS-consistent, does NOT drain vmcnt (stores/loads stay in flight)
#define BAR() asm volatile("s_waitcnt lgkmcnt(0)\n\ts_barrier" ::: "memory")

// ---- producer: burst-load x for block KB (clamped) into XR ----
#define PLOAD(XR, KB) do {                                                        \
    _Pragma("unroll")                                                             \
    for (int d = 0; d < DQ; ++d) {                                                \
        int tq = (KB) * DQ + d; if (tq > T_N - 1) tq = T_N - 1;                   \
        XR[d] = xlane[(size_t)tq * (B_N * I_N)];                                  \
    }                                                                             \
} while (0)

// ---- producer: project one block (x in XR) into buf[PAR]; f16 pack + fdot2 ----
#define PPROJ(XR, PAR) do {                                                       \
    _Pragma("unroll")                                                             \
    for (int d = 0; d < DQ; ++d) {                                                \
        const float xv  = XR[d];                                                  \
        const float xnb = dppf<0x101>(xv);               /* lane i reads i+1 */   \
        const unsigned xpk = __builtin_bit_cast(unsigned,                         \
                                 __builtin_amdgcn_cvt_pkrtz(xv, xnb));            \
        float pa = __builtin_amdgcn_fdot2(h2(rlu(xpk, 0)),  wx[0], 0.f, false);   \
        pa       = __builtin_amdgcn_fdot2(h2(rlu(xpk, 2)),  wx[1], pa,  false);   \
        pa       = __builtin_amdgcn_fdot2(h2(rlu(xpk, 4)),  wx[2], pa,  false);   \
        float pb = __builtin_amdgcn_fdot2(h2(rlu(xpk, 6)),  wx[3], 0.f, false);   \
        pb       = __builtin_amdgcn_fdot2(h2(rlu(xpk, 8)),  wx[4], pb,  false);   \
        pb       = __builtin_amdgcn_fdot2(h2(rlu(xpk, 10)), wx[5], pb,  false);   \
        float pc = __builtin_amdgcn_fdot2(h2(rlu(xpk, 12)), wx[6], 0.f, false);   \
        pc       = __builtin_amdgcn_fdot2(h2(rlu(xpk, 14)), wx[7], pc,  false);   \
        buf[PAR][d][lane] = (pa + pb) + pc;   /* lanes 40..63 land in pad */      \
    }                                                                             \
} while (0)

// ---- consumer: one LSTM step, 16-level serial cycle, pure ALU ----
// State: cs (VGPR), ths0..9 = th broadcasts, so0..9 = o broadcasts (SGPRs).
// Cycle: rl(th) -> fma x2 -> tree x2 -> exp2 -> add -> rcp -> act -> dpp ->
//        igv -> cs fma -> exp2 -> add -> rcp -> th fma -> rl.
// Off-chain: wov muls (o-fold), so readlanes, h = ov*th for output.
#define CSTEP(xav, hout) do {                                                     \
    const float w0 = so0 * wh0, w1 = so1 * wh1, w2 = so2 * wh2;                   \
    const float w3 = so3 * wh3, w4 = so4 * wh4, w5 = so5 * wh5;                   \
    const float w6 = so6 * wh6, w7 = so7 * wh7, w8 = so8 * wh8, w9 = so9 * wh9;   \
    float d0 = fmaf(ths0, w0, (xav)); d0 = fmaf(ths5, w5, d0);                    \
    float d1 = ths1 * w1;             d1 = fmaf(ths6, w6, d1);                    \
    float d2 = ths2 * w2;             d2 = fmaf(ths7, w7, d2);                    \
    float d3 = ths3 * w3;             d3 = fmaf(ths8, w8, d3);                    \
    float d4 = ths4 * w4;             d4 = fmaf(ths9, w9, d4);                    \
    const float acc = (d0 + d1 + d2) + (d3 + d4);                                 \
    const float e   = __builtin_amdgcn_exp2f(acc);                                \
    const float rc  = __builtin_amdgcn_rcpf(1.0f + e);                            \
    /* o broadcasts for NEXT step (o-rows are sigmoid: act == rc); off-chain */   \
    so0 = rl(rc, 3);  so1 = rl(rc, 7);  so2 = rl(rc, 11); so3 = rl(rc, 15);       \
    so4 = rl(rc, 19); so5 = rl(rc, 23); so6 = rl(rc, 27); so7 = rl(rc, 31);       \
    so8 = rl(rc, 35); so9 = rl(rc, 39);                                           \
    const float act = fmaf(Aact, rc, Bact);                                       \
    const float iv  = dppf<0x00>(act);                                            \
    const float fv  = dppf<0x55>(act);                                            \
    const float gv  = dppf<0xAA>(act);   /* pre-scaled by 2log2e */               \
    const float ov  = dppf<0xFF>(act);                                            \
    cs = fmaf(fv, cs, iv * gv);          /* cs = 2log2e * c */                    \
    const float tt = __builtin_amdgcn_exp2f(cs);                                  \
    const float rr = __builtin_amdgcn_rcpf(1.0f + tt);                            \
    const float th = fmaf(-2.0f, rr, 1.0f);                                       \
    h = ov * th;                          /* off-chain: output only */            \
    (hout) = h;                                                                   \
    ths0 = rl(th, 0);  ths1 = rl(th, 4);  ths2 = rl(th, 8);  ths3 = rl(th, 12);   \
    ths4 = rl(th, 16); ths5 = rl(th, 20); ths6 = rl(th, 24); ths7 = rl(th, 28);   \
    ths8 = rl(th, 32); ths9 = rl(th, 36);                                         \
} while (0)

// ---- consumer: one block: LDS->reg burst, DQ pure-ALU steps, store burst ----
#define CBLOCK(KB, PAR) do {                                                      \
    float xa[DQ];                                                                 \
    _Pragma("unroll")                                                             \
    for (int d = 0; d < DQ; ++d) xa[d] = buf[PAR][d][crow];                       \
    _Pragma("unroll")                                                             \
    for (int d = 0; d < DQ; ++d) CSTEP(xa[d], hbuf[d]);                           \
    if (writer) {                                                                 \
        _Pragma("unroll")                                                         \
        for (int d = 0; d < DQ; ++d)                                              \
            out[((size_t)(KB) * DQ + d) * (B_N * H_N) + b * H_N + j] = hbuf[d];   \
    }                                                                             \
} while (0)

__global__ __launch_bounds__(128, 2)
void lstm_pc(const float* __restrict__ x, const float* __restrict__ h0,
             const float* __restrict__ c0, const float* __restrict__ Wih,
             const float* __restrict__ Whh, float* __restrict__ out)
{
    __shared__ float buf[2][DQ][LPAD];   // 16 KB, double-buffered pre-activations

    const int tid  = threadIdx.x;
    const int wave = tid >> 6;           // 0 = consumer, 1 = producer
    const int lane = tid & 63;
    const int b    = blockIdx.x;
    const float LOG2E = 1.4426950408889634f;

    // ---- producer state ----
    half2_t wx[8];
    float xA[DQ];
    const int xk = lane < I_N ? lane : 0;
    const float* xlane = x + (size_t)b * I_N + xk;

    // ---- consumer state ----
    const int p = lane & 3;
    int j = lane >> 2; if (j > H_N - 1) j = H_N - 1;
    const int crow = p * H_N + j;
    const bool writer = (wave == 0) && (p == 0) && (lane < 4 * H_N);
    const float Aact = (p == 2) ? -4.0f * LOG2E : 1.0f;
    const float Bact = (p == 2) ?  2.0f * LOG2E : 0.0f;
    float wh0, wh1, wh2, wh3, wh4, wh5, wh6, wh7, wh8, wh9;
    float cs, h;
    float ths0, ths1, ths2, ths3, ths4, ths5, ths6, ths7, ths8, ths9;
    float so0, so1, so2, so3, so4, so5, so6, so7, so8, so9;
    float hbuf[DQ];

    if (wave == 1) {
        // producer init: prescaled Wih row for gate g = lane, packed f16 pairs
        const int g = lane < 4 * H_N ? lane : 4 * H_N - 1;
        const bool isTanhG = (g >= 2 * H_N && g < 3 * H_N);
        const float sgp = isTanhG ? 2.0f * LOG2E : -LOG2E;
#pragma unroll
        for (int m = 0; m < 7; ++m) {
            half2_t w;
            w[0] = (_Float16)(sgp * Wih[g * I_N + 2 * m]);
            w[1] = (_Float16)(sgp * Wih[g * I_N + 2 * m + 1]);
            wx[m] = w;
        }
        { half2_t w; w[0] = (_Float16)(sgp * Wih[g * I_N + 14]); w[1] = (_Float16)0.0f; wx[7] = w; }
        // prologue: project block 0 into buf[0]; stage x(block 1)
        PLOAD(xA, 0);
        PPROJ(xA, 0);
        PLOAD(xA, 1);
    } else {
        // consumer init: prescaled Whh row for gate row crow
        const float sg = (p == 2) ? 2.0f * LOG2E : -LOG2E;
        const float* wr = Whh + crow * H_N;
        wh0 = sg * wr[0]; wh1 = sg * wr[1]; wh2 = sg * wr[2]; wh3 = sg * wr[3];
        wh4 = sg * wr[4]; wh5 = sg * wr[5]; wh6 = sg * wr[6]; wh7 = sg * wr[7];
        wh8 = sg * wr[8]; wh9 = sg * wr[9];
        cs = c0[b * H_N + j] * (2.0f * LOG2E);
        h  = h0[b * H_N + j];
        // seed: h0 = 1 * h0  ->  so = 1, ths = h0
        ths0 = rl(h, 0);  ths1 = rl(h, 4);  ths2 = rl(h, 8);  ths3 = rl(h, 12);
        ths4 = rl(h, 16); ths5 = rl(h, 20); ths6 = rl(h, 24); ths7 = rl(h, 28);
        ths8 = rl(h, 32); ths9 = rl(h, 36);
        so0 = so1 = so2 = so3 = so4 = so5 = so6 = so7 = so8 = so9 = 1.0f;
        __builtin_amdgcn_s_setprio(1);   // consumer wins SIMD issue arbitration
    }
    BAR();

    // Invariant at iter m: buf[m&1] holds proj(block m); xA holds x(block m+1).
    // Producer projects block m+1 -> buf[(m+1)&1], then reloads xA = x(block m+2).
    for (int m = 0; m < NBLK; ++m) {
        if (wave == 1) {
            PPROJ(xA, (m + 1) & 1);   // garbage proj at m=63 lands in unread buf
            PLOAD(xA, m + 2);         // clamped at tail
        } else {
            CBLOCK(m, m & 1);
        }
        BAR();
    }

    // epilogue: hN, cN appended after out (flat tuple order: out, hN, cN)
    if (writer) {
        const size_t base = (size_t)T_N * B_N * H_N;
        out[base + b * H_N + j] = h;                                          // hN
        out[base + (size_t)B_N * H_N + b * H_N + j] = cs * 0.34657359027997264f; // cN
    }
}

extern "C" void kernel_launch(void* const* d_in, const int* in_sizes, int n_in,
                              void* d_out, int out_size, void* d_ws, size_t ws_size,
                              hipStream_t stream) {
    const float* x   = (const float*)d_in[0];
    const float* h0  = (const float*)d_in[1];
    const float* c0  = (const float*)d_in[2];
    const float* Wih = (const float*)d_in[3];
    const float* Whh = (const float*)d_in[4];
    float* out = (float*)d_out;
    lstm_pc<<<dim3(B_N), dim3(128), 0, stream>>>(x, h0, c0, Wih, Whh, out);
}

// Round 12
// 308.771 us; speedup vs baseline: 1.2425x; 1.2425x over previous
//
#include <hip/hip_runtime.h>

// LSTM forward, T=2048, B=1024, I=15, H=10 (PyTorch gate order i,f,g,o).
// Producer/consumer wave specialization, one 128-thread block per batch row:
//   wave 0 (consumer, s_setprio(1)): serial recurrence, pure-ALU steps
//   wave 1 (producer, s_setprio(0)): x.Wih projection (f16 fdot2) -> LDS ring
// R12 = R10 exactly + wave-priority split (single-variable test).
// R11 lesson: o-fold added ~20 consumer-stream ops for -1 chain level -> +80cy/step
// (in-order wave: own off-chain ops cost ~4cy each; a chain level is ~15cy).
// R10 accounting: step 402cy = chain(~310) + producer issue interference(~92).
// setprio should push producer issue into consumer chain-stall cycles (~75% of
// time), recovering most of the 92cy.
// Lane layout (consumer): lane = 4*j + p, j=hidden unit, p=gate; lanes 40..63
// dup j=9 (write-masked). Gate combine via DPP quad_perm. Weight prescale:
// sigmoid rows -log2e, tanh row +2log2e; g-gate act additionally scaled 2log2e
// so cell state is carried as cs = 2log2e*c and feeds exp2 directly.
// h = ov*tanh(c) = fma(-2ov, rcp(1+2^cs), ov).

#define T_N  2048
#define B_N  1024
#define I_N  15
#define H_N  10
#define DQ   32            // steps per LDS buffer
#define NBLK (T_N / DQ)    // 64 blocks
#define LPAD 64            // padded LDS row (unconditional producer writes)

typedef _Float16 half2_t __attribute__((ext_vector_type(2)));

template <int CTRL>
static __device__ __forceinline__ float dppf(float v) {
    return __builtin_bit_cast(float,
        __builtin_amdgcn_mov_dpp(__builtin_bit_cast(int, v), CTRL, 0xF, 0xF, true));
}
static __device__ __forceinline__ float rl(float v, int lane) {
    return __builtin_bit_cast(float, __builtin_amdgcn_readlane(__builtin_bit_cast(int, v), lane));
}
static __device__ __forceinline__ unsigned rlu(unsigned v, int lane) {
    return (unsigned)__builtin_amdgcn_readlane((int)v, lane);
}
static __device__ __forceinline__ half2_t h2(unsigned u) {
    return __builtin_bit_cast(half2_t, u);
}

// light barrier: LDS-consistent, does NOT drain vmcnt (stores/loads stay in flight)
#define BAR() asm volatile("s_waitcnt lgkmcnt(0)\n\ts_barrier" ::: "memory")

// ---- producer: burst-load x for block KB (clamped) into XR ----
#define PLOAD(XR, KB) do {                                                        \
    _Pragma("unroll")                                                             \
    for (int d = 0; d < DQ; ++d) {                                                \
        int tq = (KB) * DQ + d; if (tq > T_N - 1) tq = T_N - 1;                   \
        XR[d] = xlane[(size_t)tq * (B_N * I_N)];                                  \
    }                                                                             \
} while (0)

// ---- producer: project one block (x in XR) into buf[PAR]; f16 pack + fdot2 ----
#define PPROJ(XR, PAR) do {                                                       \
    _Pragma("unroll")                                                             \
    for (int d = 0; d < DQ; ++d) {                                                \
        const float xv  = XR[d];                                                  \
        const float xnb = dppf<0x101>(xv);               /* lane i reads i+1 */   \
        const unsigned xpk = __builtin_bit_cast(unsigned,                         \
                                 __builtin_amdgcn_cvt_pkrtz(xv, xnb));            \
        float pa = __builtin_amdgcn_fdot2(h2(rlu(xpk, 0)),  wx[0], 0.f, false);   \
        pa       = __builtin_amdgcn_fdot2(h2(rlu(xpk, 2)),  wx[1], pa,  false);   \
        pa       = __builtin_amdgcn_fdot2(h2(rlu(xpk, 4)),  wx[2], pa,  false);   \
        float pb = __builtin_amdgcn_fdot2(h2(rlu(xpk, 6)),  wx[3], 0.f, false);   \
        pb       = __builtin_amdgcn_fdot2(h2(rlu(xpk, 8)),  wx[4], pb,  false);   \
        pb       = __builtin_amdgcn_fdot2(h2(rlu(xpk, 10)), wx[5], pb,  false);   \
        float pc = __builtin_amdgcn_fdot2(h2(rlu(xpk, 12)), wx[6], 0.f, false);   \
        pc       = __builtin_amdgcn_fdot2(h2(rlu(xpk, 14)), wx[7], pc,  false);   \
        buf[PAR][d][lane] = (pa + pb) + pc;   /* lanes 40..63 land in pad */      \
    }                                                                             \
} while (0)

// ---- consumer: one LSTM step, ~16-level serial cycle, pure ALU ----
#define CSTEP(xav, hout) do {                                                     \
    float d0 = fmaf(hs0, wh0, (xav)); d0 = fmaf(hs5, wh5, d0);                    \
    float d1 = hs1 * wh1;             d1 = fmaf(hs6, wh6, d1);                    \
    float d2 = hs2 * wh2;             d2 = fmaf(hs7, wh7, d2);                    \
    float d3 = hs3 * wh3;             d3 = fmaf(hs8, wh8, d3);                    \
    float d4 = hs4 * wh4;             d4 = fmaf(hs9, wh9, d4);                    \
    const float acc = (d0 + d1 + d2) + (d3 + d4);     /* add3 + add + add */      \
    const float e   = __builtin_amdgcn_exp2f(acc);                                \
    const float rc  = __builtin_amdgcn_rcpf(1.0f + e);                            \
    const float act = fmaf(Aact, rc, Bact);                                       \
    const float iv  = dppf<0x00>(act);                                            \
    const float fv  = dppf<0x55>(act);                                            \
    const float gv  = dppf<0xAA>(act);   /* pre-scaled by 2log2e */               \
    const float ov  = dppf<0xFF>(act);                                            \
    const float ovm2 = -2.0f * ov;       /* off-chain */                          \
    cs = fmaf(fv, cs, iv * gv);          /* cs = 2log2e * c */                    \
    const float tt = __builtin_amdgcn_exp2f(cs);                                  \
    const float rr = __builtin_amdgcn_rcpf(1.0f + tt);                            \
    h = fmaf(ovm2, rr, ov);                                                       \
    (hout) = h;                                                                   \
    hs0 = rl(h, 0);  hs1 = rl(h, 4);  hs2 = rl(h, 8);  hs3 = rl(h, 12);           \
    hs4 = rl(h, 16); hs5 = rl(h, 20); hs6 = rl(h, 24); hs7 = rl(h, 28);           \
    hs8 = rl(h, 32); hs9 = rl(h, 36);                                             \
} while (0)

// ---- consumer: one block: LDS->reg burst, DQ pure-ALU steps, store burst ----
#define CBLOCK(KB, PAR) do {                                                      \
    float xa[DQ];                                                                 \
    _Pragma("unroll")                                                             \
    for (int d = 0; d < DQ; ++d) xa[d] = buf[PAR][d][crow];                       \
    _Pragma("unroll")                                                             \
    for (int d = 0; d < DQ; ++d) CSTEP(xa[d], hbuf[d]);                           \
    if (writer) {                                                                 \
        _Pragma("unroll")                                                         \
        for (int d = 0; d < DQ; ++d)                                              \
            out[((size_t)(KB) * DQ + d) * (B_N * H_N) + b * H_N + j] = hbuf[d];   \
    }                                                                             \
} while (0)

__global__ __launch_bounds__(128, 2)
void lstm_pc(const float* __restrict__ x, const float* __restrict__ h0,
             const float* __restrict__ c0, const float* __restrict__ Wih,
             const float* __restrict__ Whh, float* __restrict__ out)
{
    __shared__ float buf[2][DQ][LPAD];   // 16 KB, double-buffered pre-activations

    const int tid  = threadIdx.x;
    const int wave = tid >> 6;           // 0 = consumer, 1 = producer
    const int lane = tid & 63;
    const int b    = blockIdx.x;
    const float LOG2E = 1.4426950408889634f;

    // ---- producer state ----
    half2_t wx[8];
    float xA[DQ];
    const int xk = lane < I_N ? lane : 0;
    const float* xlane = x + (size_t)b * I_N + xk;

    // ---- consumer state ----
    const int p = lane & 3;
    int j = lane >> 2; if (j > H_N - 1) j = H_N - 1;
    const int crow = p * H_N + j;
    const bool writer = (wave == 0) && (p == 0) && (lane < 4 * H_N);
    const float Aact = (p == 2) ? -4.0f * LOG2E : 1.0f;
    const float Bact = (p == 2) ?  2.0f * LOG2E : 0.0f;
    float wh0, wh1, wh2, wh3, wh4, wh5, wh6, wh7, wh8, wh9;
    float cs, h;
    float hs0, hs1, hs2, hs3, hs4, hs5, hs6, hs7, hs8, hs9;
    float hbuf[DQ];

    if (wave == 1) {
        __builtin_amdgcn_s_setprio(0);   // producer: fill consumer's stall slots
        // producer init: prescaled Wih row for gate g = lane, packed f16 pairs
        const int g = lane < 4 * H_N ? lane : 4 * H_N - 1;
        const bool isTanhG = (g >= 2 * H_N && g < 3 * H_N);
        const float sgp = isTanhG ? 2.0f * LOG2E : -LOG2E;
#pragma unroll
        for (int m = 0; m < 7; ++m) {
            half2_t w;
            w[0] = (_Float16)(sgp * Wih[g * I_N + 2 * m]);
            w[1] = (_Float16)(sgp * Wih[g * I_N + 2 * m + 1]);
            wx[m] = w;
        }
        { half2_t w; w[0] = (_Float16)(sgp * Wih[g * I_N + 14]); w[1] = (_Float16)0.0f; wx[7] = w; }
        // prologue: project block 0 into buf[0]; stage x(block 1)
        PLOAD(xA, 0);
        PPROJ(xA, 0);
        PLOAD(xA, 1);
    } else {
        __builtin_amdgcn_s_setprio(1);   // consumer wins SIMD issue arbitration
        // consumer init: prescaled Whh row for gate row crow
        const float sg = (p == 2) ? 2.0f * LOG2E : -LOG2E;
        const float* wr = Whh + crow * H_N;
        wh0 = sg * wr[0]; wh1 = sg * wr[1]; wh2 = sg * wr[2]; wh3 = sg * wr[3];
        wh4 = sg * wr[4]; wh5 = sg * wr[5]; wh6 = sg * wr[6]; wh7 = sg * wr[7];
        wh8 = sg * wr[8]; wh9 = sg * wr[9];
        cs = c0[b * H_N + j] * (2.0f * LOG2E);
        h  = h0[b * H_N + j];
        hs0 = rl(h, 0);  hs1 = rl(h, 4);  hs2 = rl(h, 8);  hs3 = rl(h, 12);
        hs4 = rl(h, 16); hs5 = rl(h, 20); hs6 = rl(h, 24); hs7 = rl(h, 28);
        hs8 = rl(h, 32); hs9 = rl(h, 36);
    }
    BAR();

    // Invariant at iter m: buf[m&1] holds proj(block m); xA holds x(block m+1).
    // Producer projects block m+1 -> buf[(m+1)&1], then reloads xA = x(block m+2).
    for (int m = 0; m < NBLK; ++m) {
        if (wave == 1) {
            PPROJ(xA, (m + 1) & 1);   // garbage proj at m=63 lands in unread buf
            PLOAD(xA, m + 2);         // clamped at tail
        } else {
            CBLOCK(m, m & 1);
        }
        BAR();
    }

    // epilogue: hN, cN appended after out (flat tuple order: out, hN, cN)
    if (writer) {
        const size_t base = (size_t)T_N * B_N * H_N;
        out[base + b * H_N + j] = h;                                          // hN
        out[base + (size_t)B_N * H_N + b * H_N + j] = cs * 0.34657359027997264f; // cN
    }
}

extern "C" void kernel_launch(void* const* d_in, const int* in_sizes, int n_in,
                              void* d_out, int out_size, void* d_ws, size_t ws_size,
                              hipStream_t stream) {
    const float* x   = (const float*)d_in[0];
    const float* h0  = (const float*)d_in[1];
    const float* c0  = (const float*)d_in[2];
    const float* Wih = (const float*)d_in[3];
    const float* Whh = (const float*)d_in[4];
    float* out = (float*)d_out;
    lstm_pc<<<dim3(B_N), dim3(128), 0, stream>>>(x, h0, c0, Wih, Whh, out);
}

// Round 13
// 190.440 us; speedup vs baseline: 2.0146x; 1.6214x over previous
//
#include <hip/hip_runtime.h>

// LSTM forward, T=2048, B=1024, I=15, H=10 (PyTorch gate order i,f,g,o).
// Producer/consumer wave specialization, one 128-thread block per batch row:
//   wave 0 (consumer, prio 1): serial recurrence, pure-ALU steps; h -> LDS ring
//   wave 1 (producer, prio 0): x.Wih projection via v_mfma_f32_32x32x16_f16
//                              (2 MFMAs per 32-step block) + h global stores
// R12 lesson: producer interference ~= producer instruction count (~1.5cy per
// consumer op of port contention; setprio can't preempt in-flight ops). So this
// round shrinks producer issue ~10x: per block, the projection is one
// 32(t) x 40(gate) x 15(k) GEMM = 2 MFMAs (A = x-block f16, B = prescaled
// Wih^T, built once). Consumer's global h-stores (and their 64-bit address
// bumps) also move to the producer via an LDS h-ring (consumer: 1 ds_write
// w/ immediate offset per step).
// MFMA layouts (verified mapping, learn_hip m74/m101): D: col=lane&31,
// row=(reg&3)+8*(reg>>2)+4*(lane>>5); A: row=lane&31, k=8*(lane>>5)+e;
// B: col=lane&31, k=8*(lane>>5)+e.
// Weight prescale: sigmoid rows -log2e, tanh rows +2log2e; g-gate activation
// additionally scaled 2log2e so cell state is carried as cs = 2log2e*c and
// feeds exp2 directly. h = ov*tanh(c) = fma(-2ov, rcp(1+2^cs), ov).

#define T_N  2048
#define B_N  1024
#define I_N  15
#define H_N  10
#define DQ   32            // steps per block (= MFMA M dimension)
#define NBLK (T_N / DQ)    // 64 blocks
#define LPAD 64

typedef _Float16 f16x8  __attribute__((ext_vector_type(8)));
typedef float    f32x16 __attribute__((ext_vector_type(16)));

template <int CTRL>
static __device__ __forceinline__ float dppf(float v) {
    return __builtin_bit_cast(float,
        __builtin_amdgcn_mov_dpp(__builtin_bit_cast(int, v), CTRL, 0xF, 0xF, true));
}
static __device__ __forceinline__ float rl(float v, int lane) {
    return __builtin_bit_cast(float, __builtin_amdgcn_readlane(__builtin_bit_cast(int, v), lane));
}

// light barrier: LDS-consistent, does NOT drain vmcnt
#define BAR() asm volatile("s_waitcnt lgkmcnt(0)\n\ts_barrier" ::: "memory")

// ---- consumer: one LSTM step, ~16-level serial cycle, pure ALU ----
#define CSTEP(xav) do {                                                           \
    float d0 = fmaf(hs0, wh0, (xav)); d0 = fmaf(hs5, wh5, d0);                    \
    float d1 = hs1 * wh1;             d1 = fmaf(hs6, wh6, d1);                    \
    float d2 = hs2 * wh2;             d2 = fmaf(hs7, wh7, d2);                    \
    float d3 = hs3 * wh3;             d3 = fmaf(hs8, wh8, d3);                    \
    float d4 = hs4 * wh4;             d4 = fmaf(hs9, wh9, d4);                    \
    const float acc = (d0 + d1 + d2) + (d3 + d4);                                 \
    const float e   = __builtin_amdgcn_exp2f(acc);                                \
    const float rc  = __builtin_amdgcn_rcpf(1.0f + e);                            \
    const float act = fmaf(Aact, rc, Bact);                                       \
    const float iv  = dppf<0x00>(act);                                            \
    const float fv  = dppf<0x55>(act);                                            \
    const float gv  = dppf<0xAA>(act);   /* pre-scaled by 2log2e */               \
    const float ov  = dppf<0xFF>(act);                                            \
    const float ovm2 = -2.0f * ov;       /* off-chain */                          \
    cs = fmaf(fv, cs, iv * gv);          /* cs = 2log2e * c */                    \
    const float tt = __builtin_amdgcn_exp2f(cs);                                  \
    const float rr = __builtin_amdgcn_rcpf(1.0f + tt);                            \
    h = fmaf(ovm2, rr, ov);                                                       \
    hs0 = rl(h, 0);  hs1 = rl(h, 4);  hs2 = rl(h, 8);  hs3 = rl(h, 12);           \
    hs4 = rl(h, 16); hs5 = rl(h, 20); hs6 = rl(h, 24); hs7 = rl(h, 28);           \
    hs8 = rl(h, 32); hs9 = rl(h, 36);                                             \
} while (0)

// ---- consumer: one block: LDS->reg burst, DQ steps, h -> LDS ring ----
#define CBLOCK(PAR) do {                                                          \
    float xa[DQ];                                                                 \
    _Pragma("unroll")                                                             \
    for (int d = 0; d < DQ; ++d) xa[d] = buf[PAR][d][crow];                       \
    _Pragma("unroll")                                                             \
    for (int d = 0; d < DQ; ++d) { CSTEP(xa[d]); hsh[PAR][d][lane] = h; }         \
} while (0)

// ---- producer: load x for block KB into xr (k<15; pad 0; clamped t) ----
#define PLOADX(KB) do {                                                           \
    int t = (KB) * DQ + trow; if (t > T_N - 1) t = T_N - 1;                       \
    const float* xp = x + ((size_t)t * B_N + b) * I_N + koff;                     \
    _Pragma("unroll")                                                             \
    for (int e = 0; e < 8; ++e) xr[e] = (koff + e < I_N) ? xp[e] : 0.0f;          \
} while (0)

// ---- producer: 2 MFMAs project xr's block into buf[PAR] ----
#define PPROJ(PAR) do {                                                           \
    f16x8 af;                                                                     \
    _Pragma("unroll")                                                             \
    for (int e = 0; e < 8; ++e) af[e] = (_Float16)xr[e];                          \
    const f32x16 dA = __builtin_amdgcn_mfma_f32_32x32x16_f16(af, bf0, z16, 0, 0, 0); \
    const f32x16 dB = __builtin_amdgcn_mfma_f32_32x32x16_f16(af, bf1, z16, 0, 0, 0); \
    _Pragma("unroll")                                                             \
    for (int r = 0; r < 16; ++r) {                                                \
        const int rw = (r & 3) + 8 * (r >> 2) + rbase;                            \
        buf[PAR][rw][ncol]      = dA[r];                                          \
        buf[PAR][rw][ncol + 32] = dB[r];                                          \
    }                                                                             \
} while (0)

// ---- producer: store h block MB from LDS ring to global ----
#define HSTORE(MB) do {                                                           \
    const int par_ = (MB) & 1;                                                    \
    if (sact) {                                                                   \
        _Pragma("unroll")                                                         \
        for (int r = 0; r < 6; ++r) {                                             \
            const int dd = r * 6 + sl_d;                                          \
            if (dd < DQ)                                                          \
                out[((size_t)(MB) * DQ + dd) * (B_N * H_N) + b * H_N + sl_j]      \
                    = hsh[par_][dd][4 * sl_j];                                    \
        }                                                                         \
    }                                                                             \
} while (0)

__global__ __launch_bounds__(128, 2)
void lstm_pc(const float* __restrict__ x, const float* __restrict__ h0,
             const float* __restrict__ c0, const float* __restrict__ Wih,
             const float* __restrict__ Whh, float* __restrict__ out)
{
    __shared__ float buf[2][DQ][LPAD];   // 16 KB pre-activations (dbl-buffered)
    __shared__ float hsh[2][DQ][64];     // 16 KB h ring (dbl-buffered)

    const int tid  = threadIdx.x;
    const int wave = tid >> 6;           // 0 = consumer, 1 = producer
    const int lane = tid & 63;
    const int b    = blockIdx.x;
    const float LOG2E = 1.4426950408889634f;

    // ---- producer state ----
    const int trow  = lane & 31;         // timestep within block (A row / D row grp)
    const int koff  = (lane >> 5) * 8;   // k slice
    const int ncol  = lane & 31;         // gate column (D col)
    const int rbase = 4 * (lane >> 5);   // D row offset
    const int sl_j  = lane % H_N;        // h-store mapping
    const int sl_d  = lane / H_N;
    const bool sact = lane < 60;
    f16x8 bf0, bf1;
    f32x16 z16;
    float xr[8];

    // ---- consumer state ----
    const int p = lane & 3;
    int j = lane >> 2; if (j > H_N - 1) j = H_N - 1;
    const int crow = p * H_N + j;
    const bool writer = (wave == 0) && (p == 0) && (lane < 4 * H_N);
    const float Aact = (p == 2) ? -4.0f * LOG2E : 1.0f;
    const float Bact = (p == 2) ?  2.0f * LOG2E : 0.0f;
    float wh0, wh1, wh2, wh3, wh4, wh5, wh6, wh7, wh8, wh9;
    float cs, h;
    float hs0, hs1, hs2, hs3, hs4, hs5, hs6, hs7, hs8, hs9;

    if (wave == 1) {
        __builtin_amdgcn_s_setprio(0);
        // B fragments (constant): B[k][n] = sg(n)*Wih[n][k]; k>=15 or n>=40 -> 0
#pragma unroll
        for (int e = 0; e < 8; ++e) {
            const int k = koff + e;
            {
                const int n = ncol;
                const float sgn = (n >= 20 && n < 30) ? 2.0f * LOG2E : -LOG2E;
                bf0[e] = (_Float16)((k < I_N) ? sgn * Wih[n * I_N + k] : 0.0f);
            }
            {
                const int n = 32 + ncol;
                const float sgn = (n >= 20 && n < 30) ? 2.0f * LOG2E : -LOG2E;
                bf1[e] = (_Float16)((k < I_N && n < 40) ? sgn * Wih[n * I_N + k] : 0.0f);
            }
        }
#pragma unroll
        for (int r = 0; r < 16; ++r) z16[r] = 0.0f;
        // prologue: project block 0 into buf[0]; stage x(block 1)
        PLOADX(0);
        PPROJ(0);
        PLOADX(1);
    } else {
        __builtin_amdgcn_s_setprio(1);
        const float sg = (p == 2) ? 2.0f * LOG2E : -LOG2E;
        const float* wr = Whh + crow * H_N;
        wh0 = sg * wr[0]; wh1 = sg * wr[1]; wh2 = sg * wr[2]; wh3 = sg * wr[3];
        wh4 = sg * wr[4]; wh5 = sg * wr[5]; wh6 = sg * wr[6]; wh7 = sg * wr[7];
        wh8 = sg * wr[8]; wh9 = sg * wr[9];
        cs = c0[b * H_N + j] * (2.0f * LOG2E);
        h  = h0[b * H_N + j];
        hs0 = rl(h, 0);  hs1 = rl(h, 4);  hs2 = rl(h, 8);  hs3 = rl(h, 12);
        hs4 = rl(h, 16); hs5 = rl(h, 20); hs6 = rl(h, 24); hs7 = rl(h, 28);
        hs8 = rl(h, 32); hs9 = rl(h, 36);
    }
    BAR();

    // Invariant at iter m: buf[m&1] = proj(block m); xr = x(block m+1).
    // Producer: proj(m+1) -> buf[(m+1)&1]; load x(m+2); store h(m-1).
    // Consumer: run block m; h -> hsh[m&1].
    for (int m = 0; m < NBLK; ++m) {
        if (wave == 1) {
            PPROJ((m + 1) & 1);
            PLOADX(m + 2);
            if (m > 0) HSTORE(m - 1);
        } else {
            CBLOCK(m & 1);
        }
        BAR();
    }

    // epilogue: last h block from producer; hN/cN from consumer
    if (wave == 1) {
        HSTORE(NBLK - 1);
    } else if (writer) {
        const size_t base = (size_t)T_N * B_N * H_N;
        out[base + b * H_N + j] = h;                                          // hN
        out[base + (size_t)B_N * H_N + b * H_N + j] = cs * 0.34657359027997264f; // cN
    }
}

extern "C" void kernel_launch(void* const* d_in, const int* in_sizes, int n_in,
                              void* d_out, int out_size, void* d_ws, size_t ws_size,
                              hipStream_t stream) {
    const float* x   = (const float*)d_in[0];
    const float* h0  = (const float*)d_in[1];
    const float* c0  = (const float*)d_in[2];
    const float* Wih = (const float*)d_in[3];
    const float* Whh = (const float*)d_in[4];
    float* out = (float*)d_out;
    lstm_pc<<<dim3(B_N), dim3(128), 0, stream>>>(x, h0, c0, Wih, Whh, out);
}

// Round 14
// 182.218 us; speedup vs baseline: 2.1055x; 1.0451x over previous
//
#include <hip/hip_runtime.h>

// LSTM forward, T=2048, B=1024, I=15, H=10 (PyTorch gate order i,f,g,o).
// Producer/consumer wave specialization, one 128-thread block per batch row:
//   wave 0 (consumer, prio 1): serial recurrence, ~28 ops/step, f16 fdot2 dot
//   wave 1 (producer, prio 0): x.Wih projection via v_mfma_f32_32x32x16_f16
//                              (2 MFMAs / 32-step block) + h global stores
// R13 model: step ~= chain + ~3.5cy * own-stream ops + ~7cy * co-resident ops.
// R14 cuts consumer ops 41 -> ~28:
//   - h broadcast packed f16 (1 dpp + 1 cvt + 5 readlane) and dot via 5 fdot2
//     + 2 adds (was 10 readlane + 10 fma/mul + 4 add): -10 ops, +1 chain level.
//   - next block's 32 pre-activation ds_reads interleaved one-per-step into the
//     step stream (triple-buffered buf[3]); removes the ~300cy block-top
//     burst+lgkm stall of R13.
// MFMA layouts (verified, learn_hip m74/m101): D: col=lane&31,
// row=(reg&3)+8*(reg>>2)+4*(lane>>5); A: row=lane&31, k=8*(lane>>5)+e; B same.
// Weight prescale: sigmoid rows -log2e, tanh rows +2log2e; g-gate activation
// additionally scaled 2log2e so cell state is carried as cs = 2log2e*c and
// feeds exp2 directly. h = ov*tanh(c) = fma(-2ov, rcp(1+2^cs), ov).

#define T_N  2048
#define B_N  1024
#define I_N  15
#define H_N  10
#define DQ   32            // steps per block (= MFMA M dimension)
#define NBLK (T_N / DQ)    // 64 blocks
#define LPAD 64

typedef _Float16 half2_t __attribute__((ext_vector_type(2)));
typedef _Float16 f16x8   __attribute__((ext_vector_type(8)));
typedef float    f32x16  __attribute__((ext_vector_type(16)));

template <int CTRL>
static __device__ __forceinline__ float dppf(float v) {
    return __builtin_bit_cast(float,
        __builtin_amdgcn_mov_dpp(__builtin_bit_cast(int, v), CTRL, 0xF, 0xF, true));
}
static __device__ __forceinline__ float rl(float v, int lane) {
    return __builtin_bit_cast(float, __builtin_amdgcn_readlane(__builtin_bit_cast(int, v), lane));
}
static __device__ __forceinline__ unsigned rlu(unsigned v, int lane) {
    return (unsigned)__builtin_amdgcn_readlane((int)v, lane);
}
static __device__ __forceinline__ half2_t h2(unsigned u) {
    return __builtin_bit_cast(half2_t, u);
}

// light barrier: LDS-consistent, does NOT drain vmcnt
#define BAR() asm volatile("s_waitcnt lgkmcnt(0)\n\ts_barrier" ::: "memory")

// ---- consumer: one LSTM step, pure ALU; f16 packed h + fdot2 dot ----
// Chain: rl -> fdot2 x2 -> add x2 -> exp2 -> add -> rcp -> act -> dpp -> mul ->
//        fma(cs) -> exp2 -> add -> rcp -> fma(h) -> dpp -> cvt -> rl.
#define CSTEP(xav) do {                                                           \
    float A  = __builtin_amdgcn_fdot2(h2(hp0), wf0, (xav), false);                \
    A        = __builtin_amdgcn_fdot2(h2(hp1), wf1, A,     false);                \
    float Bv = __builtin_amdgcn_fdot2(h2(hp2), wf2, 0.f,   false);                \
    Bv       = __builtin_amdgcn_fdot2(h2(hp3), wf3, Bv,    false);                \
    const float Cv = __builtin_amdgcn_fdot2(h2(hp4), wf4, 0.f, false);            \
    const float acc = (A + Bv) + Cv;                                              \
    const float e   = __builtin_amdgcn_exp2f(acc);                                \
    const float rc  = __builtin_amdgcn_rcpf(1.0f + e);                            \
    const float act = fmaf(Aact, rc, Bact);                                       \
    const float iv  = dppf<0x00>(act);                                            \
    const float fv  = dppf<0x55>(act);                                            \
    const float gv  = dppf<0xAA>(act);   /* pre-scaled by 2log2e */               \
    const float ov  = dppf<0xFF>(act);                                            \
    const float ovm2 = -2.0f * ov;       /* off-chain */                          \
    cs = fmaf(fv, cs, iv * gv);          /* cs = 2log2e * c */                    \
    const float tt = __builtin_amdgcn_exp2f(cs);                                  \
    const float rr = __builtin_amdgcn_rcpf(1.0f + tt);                            \
    h = fmaf(ovm2, rr, ov);                                                       \
    const float hbv = dppf<0x104>(h);    /* row_shl:4 -> lane i reads i+4 */      \
    const unsigned pkh = __builtin_bit_cast(unsigned,                             \
                             __builtin_amdgcn_cvt_pkrtz(h, hbv));                 \
    hp0 = rlu(pkh, 0); hp1 = rlu(pkh, 8); hp2 = rlu(pkh, 16);                     \
    hp3 = rlu(pkh, 24); hp4 = rlu(pkh, 32);                                       \
} while (0)

// ---- consumer: one block: DQ steps on XC; prefetch next block into XN
//      (one ds_read per step, slot SLOTN); h -> hsh[PAR] (one ds_write/step) ----
#define CBLOCK(XC, XN, SLOTN, PAR) do {                                           \
    const float* nb = &buf[SLOTN][0][crow];                                       \
    _Pragma("unroll")                                                             \
    for (int d = 0; d < DQ; ++d) {                                                \
        CSTEP(XC[d]);                                                             \
        XN[d] = nb[d * LPAD];                                                     \
        hsh[PAR][d][lane] = h;                                                    \
    }                                                                             \
} while (0)

// ---- producer: load x for block KB into xr (k<15; pad 0; clamped t) ----
#define PLOADX(KB) do {                                                           \
    int t = (KB) * DQ + trow; if (t > T_N - 1) t = T_N - 1;                       \
    const float* xp = x + ((size_t)t * B_N + b) * I_N + koff;                     \
    _Pragma("unroll")                                                             \
    for (int e = 0; e < 8; ++e) xr[e] = (koff + e < I_N) ? xp[e] : 0.0f;          \
} while (0)

// ---- producer: 2 MFMAs project xr's block into buf[SLOT] ----
#define PPROJ(SLOT) do {                                                          \
    f16x8 af;                                                                     \
    _Pragma("unroll")                                                             \
    for (int e = 0; e < 8; ++e) af[e] = (_Float16)xr[e];                          \
    const f32x16 dA = __builtin_amdgcn_mfma_f32_32x32x16_f16(af, bf0, z16, 0, 0, 0); \
    const f32x16 dB = __builtin_amdgcn_mfma_f32_32x32x16_f16(af, bf1, z16, 0, 0, 0); \
    _Pragma("unroll")                                                             \
    for (int r = 0; r < 16; ++r) {                                                \
        const int rw = (r & 3) + 8 * (r >> 2) + rbase;                            \
        buf[SLOT][rw][ncol]      = dA[r];                                         \
        buf[SLOT][rw][ncol + 32] = dB[r];   /* cols 40..63 land in pad */         \
    }                                                                             \
} while (0)

// ---- producer: store h block MB from LDS ring to global ----
#define HSTORE(MB) do {                                                           \
    const int par_ = (MB) & 1;                                                    \
    if (sact) {                                                                   \
        _Pragma("unroll")                                                         \
        for (int r = 0; r < 6; ++r) {                                             \
            const int dd = r * 6 + sl_d;                                          \
            if (dd < DQ)                                                          \
                out[((size_t)(MB) * DQ + dd) * (B_N * H_N) + b * H_N + sl_j]      \
                    = hsh[par_][dd][4 * sl_j];                                    \
        }                                                                         \
    }                                                                             \
} while (0)

__global__ __launch_bounds__(128, 2)
void lstm_pc(const float* __restrict__ x, const float* __restrict__ h0,
             const float* __restrict__ c0, const float* __restrict__ Wih,
             const float* __restrict__ Whh, float* __restrict__ out)
{
    __shared__ float buf[3][DQ][LPAD];   // 24 KB pre-activations (triple-buffered)
    __shared__ float hsh[2][DQ][64];     // 16 KB h ring (double-buffered)

    const int tid  = threadIdx.x;
    const int wave = tid >> 6;           // 0 = consumer, 1 = producer
    const int lane = tid & 63;
    const int b    = blockIdx.x;
    const float LOG2E = 1.4426950408889634f;

    // ---- producer state ----
    const int trow  = lane & 31;         // timestep within block (A row)
    const int koff  = (lane >> 5) * 8;   // k slice
    const int ncol  = lane & 31;         // gate column (D col)
    const int rbase = 4 * (lane >> 5);   // D row offset
    const int sl_j  = lane % H_N;        // h-store mapping
    const int sl_d  = lane / H_N;
    const bool sact = lane < 60;
    f16x8 bf0, bf1;
    f32x16 z16;
    float xr[8];

    // ---- consumer state ----
    const int p = lane & 3;
    int j = lane >> 2; if (j > H_N - 1) j = H_N - 1;
    const int crow = p * H_N + j;
    const bool writer = (wave == 0) && (p == 0) && (lane < 4 * H_N);
    const float Aact = (p == 2) ? -4.0f * LOG2E : 1.0f;
    const float Bact = (p == 2) ?  2.0f * LOG2E : 0.0f;
    half2_t wf0, wf1, wf2, wf3, wf4;     // prescaled Whh row, f16 pairs
    float cs, h;
    unsigned hp0, hp1, hp2, hp3, hp4;    // packed f16 h pairs (SGPR-broadcast)
    float xqA[DQ], xqB[DQ];

    if (wave == 1) {
        __builtin_amdgcn_s_setprio(0);
        // B fragments (constant): B[k][n] = sg(n)*Wih[n][k]; k>=15 or n>=40 -> 0
#pragma unroll
        for (int e = 0; e < 8; ++e) {
            const int k = koff + e;
            {
                const int n = ncol;
                const float sgn = (n >= 20 && n < 30) ? 2.0f * LOG2E : -LOG2E;
                bf0[e] = (_Float16)((k < I_N) ? sgn * Wih[n * I_N + k] : 0.0f);
            }
            {
                const int n = 32 + ncol;
                const float sgn = (n >= 20 && n < 30) ? 2.0f * LOG2E : -LOG2E;
                bf1[e] = (_Float16)((k < I_N && n < 40) ? sgn * Wih[n * I_N + k] : 0.0f);
            }
        }
#pragma unroll
        for (int r = 0; r < 16; ++r) z16[r] = 0.0f;
        // prologue: proj(0)->slot0, proj(1)->slot1; stage x(block 2)
        PLOADX(0);
        PPROJ(0);
        PLOADX(1);
        PPROJ(1);
        PLOADX(2);
    } else {
        __builtin_amdgcn_s_setprio(1);
        // prescaled Whh row for gate row crow, packed f16 pairs
        const float sg = (p == 2) ? 2.0f * LOG2E : -LOG2E;
        const float* wr = Whh + crow * H_N;
        half2_t w;
        w[0] = (_Float16)(sg * wr[0]); w[1] = (_Float16)(sg * wr[1]); wf0 = w;
        w[0] = (_Float16)(sg * wr[2]); w[1] = (_Float16)(sg * wr[3]); wf1 = w;
        w[0] = (_Float16)(sg * wr[4]); w[1] = (_Float16)(sg * wr[5]); wf2 = w;
        w[0] = (_Float16)(sg * wr[6]); w[1] = (_Float16)(sg * wr[7]); wf3 = w;
        w[0] = (_Float16)(sg * wr[8]); w[1] = (_Float16)(sg * wr[9]); wf4 = w;
        cs = c0[b * H_N + j] * (2.0f * LOG2E);
        h  = h0[b * H_N + j];
        const float hbv = dppf<0x104>(h);
        const unsigned pkh = __builtin_bit_cast(unsigned,
                                 __builtin_amdgcn_cvt_pkrtz(h, hbv));
        hp0 = rlu(pkh, 0); hp1 = rlu(pkh, 8); hp2 = rlu(pkh, 16);
        hp3 = rlu(pkh, 24); hp4 = rlu(pkh, 32);
    }
    BAR();   // slot0/slot1 projections visible

    // consumer: one-time burst read of block 0 (the only block-top stall)
    if (wave == 0) {
#pragma unroll
        for (int d = 0; d < DQ; ++d) xqA[d] = buf[0][d][crow];
    }

    // Slot rotation invariant at iter i: consumer consumes regs (block i),
    // prefetches block i+1 from slot slR; producer projects block i+2 into slW.
    // After BAR: (slO, slR, slW) <- (slR, slW, slO).
    int slR = 1, slW = 2, slO = 0;
    for (int m = 0; m < NBLK; m += 2) {
        // iter m (even): consume xqA -> prefetch xqB; hsh parity 0
        if (wave == 1) {
            PPROJ(slW);
            PLOADX(m + 3);
            if (m > 0) HSTORE(m - 1);
        } else {
            CBLOCK(xqA, xqB, slR, 0);
        }
        BAR();
        { const int t = slO; slO = slR; slR = slW; slW = t; }
        // iter m+1 (odd): consume xqB -> prefetch xqA; hsh parity 1
        if (wave == 1) {
            PPROJ(slW);
            PLOADX(m + 4);
            HSTORE(m);
        } else {
            CBLOCK(xqB, xqA, slR, 1);
        }
        BAR();
        { const int t = slO; slO = slR; slR = slW; slW = t; }
    }

    // epilogue: last h block from producer; hN/cN from consumer
    if (wave == 1) {
        HSTORE(NBLK - 1);
    } else if (writer) {
        const size_t base = (size_t)T_N * B_N * H_N;
        out[base + b * H_N + j] = h;                                          // hN
        out[base + (size_t)B_N * H_N + b * H_N + j] = cs * 0.34657359027997264f; // cN
    }
}

extern "C" void kernel_launch(void* const* d_in, const int* in_sizes, int n_in,
                              void* d_out, int out_size, void* d_ws, size_t ws_size,
                              hipStream_t stream) {
    const float* x   = (const float*)d_in[0];
    const float* h0  = (const float*)d_in[1];
    const float* c0  = (const float*)d_in[2];
    const float* Wih = (const float*)d_in[3];
    const float* Whh = (const float*)d_in[4];
    float* out = (float*)d_out;
    lstm_pc<<<dim3(B_N), dim3(128), 0, stream>>>(x, h0, c0, Wih, Whh, out);
}